// Round 4
// baseline (4561.284 us; speedup 1.0000x reference)
//
#include <hip/hip_runtime.h>
#include <math.h>

#define B 32
#define T 128
#define H 512
#define E 512
#define ODIM 256
#define STEPS 16
#define G3 1536  // 3*H
#define BH (B * H)

typedef float4 f4;

__device__ __forceinline__ float sigmoidf_(float x) { return 1.0f / (1.0f + __expf(-x)); }
__device__ __forceinline__ void fma4(f4& a, float s, const f4 w) {
    a.x = fmaf(s, w.x, a.x); a.y = fmaf(s, w.y, a.y);
    a.z = fmaf(s, w.z, a.z); a.w = fmaf(s, w.w, a.w);
}
__device__ __forceinline__ void add4(f4& a, const f4 b) {
    a.x += b.x; a.y += b.y; a.z += b.z; a.w += b.w;
}

// ---------------- generic 32x32 tiled transpose: out[c*R+r] = in[r*ldin+c] ----------------
__global__ void transpose_kernel(const float* __restrict__ in, float* __restrict__ out,
                                 int R, int C, int ldin) {
    __shared__ float tile[32][33];
    int r0 = blockIdx.x * 32, c0 = blockIdx.y * 32;
    int tx = threadIdx.x & 31, ty = threadIdx.x >> 5;  // 32x8
#pragma unroll
    for (int k = 0; k < 4; ++k) {
        int r = r0 + ty + k * 8;
        tile[ty + k * 8][tx] = in[(size_t)r * ldin + c0 + tx];
    }
    __syncthreads();
#pragma unroll
    for (int k = 0; k < 4; ++k) {
        int c = c0 + ty + k * 8;
        out[(size_t)c * R + r0 + tx] = tile[tx][ty + k * 8];
    }
}

// ---------------- kpT[b][c][t] = sum_k enc[b*T+t][k] * WkT[k][c] ----------------
__global__ void __launch_bounds__(256) kproj_gemm_kernel(const float* __restrict__ A,
                                                         const float* __restrict__ Bt,
                                                         float* __restrict__ kpT) {
    __shared__ float As[64][68];
    __shared__ float Bs[64][64];
    int r0 = blockIdx.x * 64, c0 = blockIdx.y * 64;
    int tid = threadIdx.x;
    int tx = tid & 15, ty = tid >> 4;  // 16x16, 4x4 micro-tile
    float acc[4][4] = {};
    for (int k0 = 0; k0 < 512; k0 += 64) {
#pragma unroll
        for (int i = 0; i < 4; ++i) {
            int row = i * 16 + ty, col = tx * 4;
            f4 av = *(const f4*)(A + (size_t)(r0 + row) * 512 + k0 + col);
            As[row][col] = av.x; As[row][col + 1] = av.y; As[row][col + 2] = av.z; As[row][col + 3] = av.w;
            f4 bv = *(const f4*)(Bt + (size_t)(k0 + row) * 512 + c0 + col);
            *(f4*)&Bs[row][col] = bv;
        }
        __syncthreads();
#pragma unroll 8
        for (int kk = 0; kk < 64; ++kk) {
            float a[4];
#pragma unroll
            for (int i = 0; i < 4; ++i) a[i] = As[ty * 4 + i][kk];
            f4 bv = *(const f4*)&Bs[kk][tx * 4];
#pragma unroll
            for (int i = 0; i < 4; ++i) {
                acc[i][0] += a[i] * bv.x; acc[i][1] += a[i] * bv.y;
                acc[i][2] += a[i] * bv.z; acc[i][3] += a[i] * bv.w;
            }
        }
        __syncthreads();
    }
#pragma unroll
    for (int i = 0; i < 4; ++i) {
        int r = r0 + ty * 4 + i;
        int b = r >> 7, t = r & 127;
#pragma unroll
        for (int j = 0; j < 4; ++j) {
            int c = c0 + tx * 4 + j;
            kpT[((size_t)b * H + c) * T + t] = acc[i][j];
        }
    }
}

// ---------------- init: copy hidden, inp = emb(ones)*SOS ----------------
__global__ void __launch_bounds__(512) init_kernel(const float* __restrict__ hidden,
                                                   const float* __restrict__ embWT,
                                                   const float* __restrict__ emb_b,
                                                   float* __restrict__ h0, float* __restrict__ h1,
                                                   float* __restrict__ inp) {
    int b = blockIdx.x, tid = threadIdx.x;
    h0[b * H + tid] = hidden[b * H + tid];
    h1[b * H + tid] = hidden[BH + b * H + tid];
    float acc = emb_b[tid];
#pragma unroll 8
    for (int o = 0; o < ODIM; ++o) acc += embWT[o * E + tid];
    inp[b * E + tid] = acc;
}

// ---------------- attn1: qproj (blocks<nb_q: 128 = 32b x 4 js) + lin(i-1) (32 blocks) ----------------
__global__ void __launch_bounds__(256) attn1_kernel(
    int nb_q, const float* __restrict__ h1cur, const float* __restrict__ WqT,
    float* __restrict__ q,
    const float* __restrict__ lastWT, const float* __restrict__ last_b,
    const float* __restrict__ target_step, const int* __restrict__ mask_step,
    float* __restrict__ f, float* __restrict__ out_step) {
    __shared__ __align__(16) f4 shh[128];
    __shared__ __align__(16) f4 part[256];
    int tid = threadIdx.x;
    if ((int)blockIdx.x < nb_q) {
        int b = blockIdx.x >> 2, js = blockIdx.x & 3;
        if (tid < 128) shh[tid] = ((const f4*)(h1cur + (size_t)b * H))[tid];
        __syncthreads();
        int jq = tid & 31, ks = tid >> 5;  // 8 ks x 64 k
        const f4* w4 = (const f4*)WqT;
        const float* hs = (const float*)shh;
        f4 acc = {0, 0, 0, 0};
        int k0 = ks * 64;
#pragma unroll 8
        for (int k = k0; k < k0 + 64; ++k) fma4(acc, hs[k], w4[(size_t)k * 128 + js * 32 + jq]);
        part[tid] = acc;
        __syncthreads();
        if (tid < 32) {
            f4 s = part[tid];
#pragma unroll
            for (int r = 1; r < 8; ++r) add4(s, part[r * 32 + tid]);
            ((f4*)(q + (size_t)b * H))[js * 32 + tid] = s;
        }
    } else {
        int b = blockIdx.x - nb_q;
        if (tid < 128) shh[tid] = ((const f4*)(h1cur + (size_t)b * H))[tid];
        __syncthreads();
        int oq = tid & 63, ks = tid >> 6;  // 4 ks x 128 k
        const f4* w4 = (const f4*)lastWT;
        const float* hs = (const float*)shh;
        f4 acc = {0, 0, 0, 0};
        int k0 = ks * 128;
#pragma unroll 8
        for (int k = k0; k < k0 + 128; ++k) fma4(acc, hs[k], w4[(size_t)k * 64 + oq]);
        part[tid] = acc;
        __syncthreads();
        if (tid < 64) {
            f4 s = part[tid];
            add4(s, part[64 + tid]); add4(s, part[128 + tid]); add4(s, part[192 + tid]);
            add4(s, ((const f4*)last_b)[tid]);
            f4 tg = ((const f4*)(target_step + (size_t)b * ODIM))[tid];
            int m = mask_step[b];
            f4 ff;
            ff.x = m ? tg.x : s.x; ff.y = m ? tg.y : s.y;
            ff.z = m ? tg.z : s.z; ff.w = m ? tg.w : s.w;
            ((f4*)(f + (size_t)b * ODIM))[tid] = ff;
            ((f4*)(out_step + (size_t)b * ODIM))[tid] = ff;
        }
    }
}

// ---------------- attn2: scores+softmax+ctx (32 blocks) + emb(i-1) (32 blocks) ----------------
__global__ void __launch_bounds__(256) attn2_kernel(
    int nb_a, const float* __restrict__ q, const float* __restrict__ kpT,
    const float* __restrict__ wv, const float* __restrict__ enc,
    float* __restrict__ ctx, float* __restrict__ attn_out,
    const float* __restrict__ f, const float* __restrict__ embWT,
    const float* __restrict__ emb_b, float* __restrict__ inp) {
    __shared__ __align__(16) float shq[H];
    __shared__ __align__(16) float shwv[H];
    __shared__ float part[256];
    __shared__ __align__(16) f4 part4[256];
    __shared__ float sw[T];
    __shared__ float red[4];
    int tid = threadIdx.x;
    if ((int)blockIdx.x < nb_a) {
        int b = blockIdx.x;
        if (tid < 128) {
            ((f4*)shq)[tid] = ((const f4*)(q + (size_t)b * H))[tid];
            ((f4*)shwv)[tid] = ((const f4*)wv)[tid];
        }
        __syncthreads();
        // scores
        {
            int t = tid & 127, half = tid >> 7;
            const float* kp = kpT + (size_t)b * H * T + (size_t)half * 256 * T + t;
            float sa = 0.f;
#pragma unroll 4
            for (int j = 0; j < 256; ++j) {
                int jj = half * 256 + j;
                sa += tanhf(shq[jj] + kp[(size_t)j * T]) * shwv[jj];
            }
            part[tid] = sa;
        }
        __syncthreads();
        float scv = 0.f;
        if (tid < 128) {
            scv = part[tid] + part[128 + tid];
            float m = scv;
            for (int off = 32; off; off >>= 1) m = fmaxf(m, __shfl_xor(m, off));
            if ((tid & 63) == 0) red[tid >> 6] = m;
        }
        __syncthreads();
        if (tid < 128) {
            float M = fmaxf(red[0], red[1]);
            float e = __expf(scv - M);
            sw[tid] = e;
            float s = e;
            for (int off = 32; off; off >>= 1) s += __shfl_xor(s, off);
            if ((tid & 63) == 0) red[2 + (tid >> 6)] = s;
        }
        __syncthreads();
        if (tid < 128) {
            float w = sw[tid] / (red[2] + red[3]);
            sw[tid] = w;
            attn_out[(size_t)b * T + tid] = w;
        }
        __syncthreads();
        // ctx
        {
            int cq = tid & 127, th = tid >> 7;
            const f4* e4 = (const f4*)enc;
            f4 acc = {0, 0, 0, 0};
            int t0 = th * 64;
#pragma unroll 8
            for (int t2 = t0; t2 < t0 + 64; ++t2)
                fma4(acc, sw[t2], e4[((size_t)b * T + t2) * 128 + cq]);
            part4[tid] = acc;
        }
        __syncthreads();
        if (tid < 128) {
            f4 s = part4[tid];
            add4(s, part4[128 + tid]);
            ((f4*)(ctx + (size_t)b * H))[tid] = s;
        }
    } else {
        int b = blockIdx.x - nb_a;
        if (tid < 64) ((f4*)shq)[tid] = ((const f4*)(f + (size_t)b * ODIM))[tid];
        __syncthreads();
        int eq = tid & 127, os = tid >> 7;  // 2 x 128 o
        const f4* w4 = (const f4*)embWT;
        f4 acc = {0, 0, 0, 0};
        int o0 = os * 128;
#pragma unroll 8
        for (int o = o0; o < o0 + 128; ++o) fma4(acc, shq[o], w4[(size_t)o * 128 + eq]);
        part4[tid] = acc;
        __syncthreads();
        if (tid < 128) {
            f4 s = part4[tid];
            add4(s, part4[128 + tid]);
            add4(s, ((const f4*)emb_b)[tid]);
            ((f4*)(inp + (size_t)b * E))[tid] = s;
        }
    }
}

// ---------------- gi: blocks 0..95 gi_ctx = bi0 + ctx@Wi0aT ; 96..191 gi_emb[i] = inp@Wi0bT ----------------
// block: cb = lbid/8 (12 x 128 cols), bblk = lbid%8 (4 b); thread: cq = tid&31 (f4 col), ks = tid>>5 (8 x 64k)
__global__ void __launch_bounds__(256) gi_kernel(
    const float* __restrict__ ctx, const float* __restrict__ Wi0aT,
    const float* __restrict__ bi0, float* __restrict__ gi_ctx,
    const float* __restrict__ inp, const float* __restrict__ Wi0bT,
    float* __restrict__ gi_emb_i) {
    __shared__ __align__(16) f4 stage[512];   // [k][4b]
    __shared__ __align__(16) f4 partb[1024];  // tid*4 + bi
    int tid = threadIdx.x;
    int lbid = blockIdx.x;
    bool isC = lbid < 96;
    if (!isC) lbid -= 96;
    const float* src = isC ? ctx : inp;
    const float* W = isC ? Wi0aT : Wi0bT;
    float* dst = isC ? gi_ctx : gi_emb_i;
    int cb = lbid >> 3, bblk = lbid & 7, b0 = bblk * 4;
    {
        float* sf = (float*)stage;
#pragma unroll
        for (int r = 0; r < 2; ++r) {
            int idx = r * 256 + tid;
            int bb = idx >> 7, kq = idx & 127;
            f4 v = ((const f4*)(src + (size_t)(b0 + bb) * H))[kq];
            sf[(kq * 4 + 0) * 4 + bb] = v.x; sf[(kq * 4 + 1) * 4 + bb] = v.y;
            sf[(kq * 4 + 2) * 4 + bb] = v.z; sf[(kq * 4 + 3) * 4 + bb] = v.w;
        }
    }
    __syncthreads();
    int cq = tid & 31, ks = tid >> 5;
    const f4* w4 = (const f4*)W;
    f4 a0 = {0, 0, 0, 0}, a1 = {0, 0, 0, 0}, a2 = {0, 0, 0, 0}, a3 = {0, 0, 0, 0};
    int k0 = ks * 64;
#pragma unroll 4
    for (int k = k0; k < k0 + 64; ++k) {
        f4 s = stage[k];
        f4 w = w4[(size_t)k * 384 + cb * 32 + cq];
        fma4(a0, s.x, w); fma4(a1, s.y, w); fma4(a2, s.z, w); fma4(a3, s.w, w);
    }
    partb[tid * 4 + 0] = a0; partb[tid * 4 + 1] = a1;
    partb[tid * 4 + 2] = a2; partb[tid * 4 + 3] = a3;
    __syncthreads();
    if (tid < 128) {
        int cq2 = tid & 31, bi = tid >> 5;
        f4 s = partb[cq2 * 4 + bi];
#pragma unroll
        for (int k = 1; k < 8; ++k) add4(s, partb[(k * 32 + cq2) * 4 + bi]);
        if (isC) add4(s, ((const f4*)bi0)[cb * 32 + cq2]);
        ((f4*)dst)[(size_t)(b0 + bi) * 384 + cb * 32 + cq2] = s;
    }
}

// ---------------- fused dual GRU cell, all-b col-sliced ----------------
// l0 blocks [0,nb0=64): jb = bid>>2 (16 x 32 j), bblk = bid&3 (8 b)
// l1 blocks [nb0,nb0+128): jb = lb>>2 (32 x 16 j), bblk = lb&3 (8 b)
__global__ void __launch_bounds__(256) cell_kernel(
    int nb0,
    const float* __restrict__ h0_src, float* __restrict__ h0_dst,
    const float* __restrict__ h1_src, float* __restrict__ h1_dst,
    const float* __restrict__ gi_emb_t, const float* __restrict__ gi_ctx,
    const float* __restrict__ Wh0T, const float* __restrict__ bh0,
    const float* __restrict__ Wi1T, const float* __restrict__ bi1,
    const float* __restrict__ Wh1T, const float* __restrict__ bh1) {
    __shared__ __align__(16) float stA[4096];  // [k][8b]
    __shared__ __align__(16) float stB[4096];
    __shared__ __align__(16) f4 part4[1536];   // 24 KB
    float* part = (float*)part4;
    int tid = threadIdx.x;
    if ((int)blockIdx.x < nb0) {
        int jb = blockIdx.x >> 2, bblk = blockIdx.x & 3, b0 = bblk * 8, j0 = jb * 32;
#pragma unroll
        for (int r = 0; r < 4; ++r) {
            int idx = r * 256 + tid;
            int bb = idx >> 7, kq = idx & 127;
            f4 v = ((const f4*)(h0_src + (size_t)(b0 + bb) * H))[kq];
            stA[(kq * 4 + 0) * 8 + bb] = v.x; stA[(kq * 4 + 1) * 8 + bb] = v.y;
            stA[(kq * 4 + 2) * 8 + bb] = v.z; stA[(kq * 4 + 3) * 8 + bb] = v.w;
        }
        __syncthreads();
        int j = tid & 31, bq = (tid >> 5) & 1, ks = tid >> 6;  // 4 ks x 128 k
        f4 a0 = {0, 0, 0, 0}, a1 = {0, 0, 0, 0}, a2 = {0, 0, 0, 0};
        int k0 = ks * 128;
        const float* wbase = Wh0T + j0 + j;
#pragma unroll 4
        for (int k = k0; k < k0 + 128; ++k) {
            float w0 = wbase[(size_t)k * G3];
            float w1 = wbase[(size_t)k * G3 + 512];
            float w2 = wbase[(size_t)k * G3 + 1024];
            f4 hv = *(const f4*)(stA + k * 8 + bq * 4);
            fma4(a0, w0, hv); fma4(a1, w1, hv); fma4(a2, w2, hv);
        }
        part4[tid * 3 + 0] = a0; part4[tid * 3 + 1] = a1; part4[tid * 3 + 2] = a2;
        __syncthreads();
        // final: 256 thr = j(32) x b(8)
        int fj = tid & 31, fb = tid >> 5, fbq = fb >> 2, fbi = fb & 3;
        float gh[3];
#pragma unroll
        for (int g = 0; g < 3; ++g) {
            float s = 0.f;
#pragma unroll
            for (int k = 0; k < 4; ++k) s += part[((k * 64 + fbq * 32 + fj) * 3 + g) * 4 + fbi];
            gh[g] = s;
        }
        int jg = j0 + fj, bg = b0 + fb;
        float gir = gi_ctx[bg * G3 + jg] + gi_emb_t[bg * G3 + jg];
        float giz = gi_ctx[bg * G3 + 512 + jg] + gi_emb_t[bg * G3 + 512 + jg];
        float gin = gi_ctx[bg * G3 + 1024 + jg] + gi_emb_t[bg * G3 + 1024 + jg];
        float r = sigmoidf_(gir + gh[0] + bh0[jg]);
        float z = sigmoidf_(giz + gh[1] + bh0[512 + jg]);
        float n = tanhf(gin + r * (gh[2] + bh0[1024 + jg]));
        h0_dst[bg * H + jg] = (1.0f - z) * n + z * stA[jg * 8 + fb];
    } else {
        int lb = blockIdx.x - nb0;
        int jb = lb >> 2, bblk = lb & 3, b0 = bblk * 8, j0 = jb * 16;
#pragma unroll
        for (int r = 0; r < 4; ++r) {
            int idx = r * 256 + tid;
            int bb = idx >> 7, kq = idx & 127;
            f4 v = ((const f4*)(h0_src + (size_t)(b0 + bb) * H))[kq];
            stA[(kq * 4 + 0) * 8 + bb] = v.x; stA[(kq * 4 + 1) * 8 + bb] = v.y;
            stA[(kq * 4 + 2) * 8 + bb] = v.z; stA[(kq * 4 + 3) * 8 + bb] = v.w;
            f4 u = ((const f4*)(h1_src + (size_t)(b0 + bb) * H))[kq];
            stB[(kq * 4 + 0) * 8 + bb] = u.x; stB[(kq * 4 + 1) * 8 + bb] = u.y;
            stB[(kq * 4 + 2) * 8 + bb] = u.z; stB[(kq * 4 + 3) * 8 + bb] = u.w;
        }
        __syncthreads();
        int j = tid & 15, bq = (tid >> 4) & 1, ks = tid >> 5;  // 8 ks x 64 k
        f4 i0 = {0, 0, 0, 0}, i1 = {0, 0, 0, 0}, i2 = {0, 0, 0, 0};
        f4 g0 = {0, 0, 0, 0}, g1 = {0, 0, 0, 0}, g2 = {0, 0, 0, 0};
        int k0 = ks * 64;
        const float* wib = Wi1T + j0 + j;
        const float* whb = Wh1T + j0 + j;
#pragma unroll 4
        for (int k = k0; k < k0 + 64; ++k) {
            float wi0 = wib[(size_t)k * G3];
            float wi1 = wib[(size_t)k * G3 + 512];
            float wi2 = wib[(size_t)k * G3 + 1024];
            float wh0 = whb[(size_t)k * G3];
            float wh1 = whb[(size_t)k * G3 + 512];
            float wh2 = whb[(size_t)k * G3 + 1024];
            f4 xv = *(const f4*)(stA + k * 8 + bq * 4);
            f4 hv = *(const f4*)(stB + k * 8 + bq * 4);
            fma4(i0, wi0, xv); fma4(i1, wi1, xv); fma4(i2, wi2, xv);
            fma4(g0, wh0, hv); fma4(g1, wh1, hv); fma4(g2, wh2, hv);
        }
        f4* p6 = part4 + tid * 6;
        p6[0] = i0; p6[1] = i1; p6[2] = i2; p6[3] = g0; p6[4] = g1; p6[5] = g2;
        __syncthreads();
        if (tid < 128) {
            int fj = tid & 15, fb = tid >> 4, fbq = fb >> 2, fbi = fb & 3;
            float si[3], sh[3];
#pragma unroll
            for (int g = 0; g < 3; ++g) {
                float s1 = 0.f, s2 = 0.f;
#pragma unroll
                for (int k = 0; k < 8; ++k) {
                    int base = (k * 32 + fbq * 16 + fj) * 24;
                    s1 += part[base + g * 4 + fbi];
                    s2 += part[base + 12 + g * 4 + fbi];
                }
                si[g] = s1; sh[g] = s2;
            }
            int jg = j0 + fj, bg = b0 + fb;
            float r = sigmoidf_(si[0] + bi1[jg] + sh[0] + bh1[jg]);
            float z = sigmoidf_(si[1] + bi1[512 + jg] + sh[1] + bh1[512 + jg]);
            float n = tanhf(si[2] + bi1[1024 + jg] + r * (sh[2] + bh1[1024 + jg]));
            h1_dst[bg * H + jg] = (1.0f - z) * n + z * stB[jg * 8 + fb];
        }
    }
}

__global__ void copy_hidden_kernel(const float* __restrict__ h0, const float* __restrict__ h1,
                                   float* __restrict__ dst) {
    int i = blockIdx.x * 256 + threadIdx.x;
    dst[i] = h0[i];
    dst[BH + i] = h1[i];
}

extern "C" void kernel_launch(void* const* d_in, const int* in_sizes, int n_in,
                              void* d_out_v, int out_size, void* d_ws, size_t ws_size,
                              hipStream_t stream) {
    const float* enc = (const float*)d_in[0];
    const float* hidden = (const float*)d_in[1];
    const float* target = (const float*)d_in[2];
    const float* Wq = (const float*)d_in[3];
    const float* Wk = (const float*)d_in[4];
    const float* wv = (const float*)d_in[5];
    const float* emb_W = (const float*)d_in[6];
    const float* emb_b = (const float*)d_in[7];
    const float* Wi0 = (const float*)d_in[8];
    const float* Wh0 = (const float*)d_in[9];
    const float* bi0 = (const float*)d_in[10];
    const float* bh0 = (const float*)d_in[11];
    const float* Wi1 = (const float*)d_in[12];
    const float* Wh1 = (const float*)d_in[13];
    const float* bi1 = (const float*)d_in[14];
    const float* bh1 = (const float*)d_in[15];
    const float* last_W = (const float*)d_in[16];
    const float* last_b = (const float*)d_in[17];
    const int* tmask = (const int*)d_in[18];

    float* out = (float*)d_out_v;
    float* out_hidden = out + (size_t)STEPS * B * ODIM;
    float* out_attn = out_hidden + (size_t)2 * BH;

    float* ws = (float*)d_ws;
    float* kpT = ws;                        // 2,097,152
    float* WqT = kpT + 2097152;             // 262,144
    float* WkT = WqT + 262144;              // 262,144
    float* Wi0aT = WkT + 262144;            // 786,432
    float* Wi0bT = Wi0aT + 786432;          // 786,432
    float* Wh0T = Wi0bT + 786432;           // 786,432
    float* Wi1T = Wh0T + 786432;            // 786,432
    float* Wh1T = Wi1T + 786432;            // 786,432
    float* lastWT = Wh1T + 786432;          // 131,072
    float* embWT = lastWT + 131072;         // 131,072
    float* gi_emb = embWT + 131072;         // 786,432 (16 steps)
    float* gi_ctx = gi_emb + 786432;        // 49,152
    float* h0buf = gi_ctx + 49152;          // 32,768
    float* h1buf = h0buf + 32768;           // 32,768
    float* qbuf = h1buf + 32768;            // 16,384
    float* ctxbuf = qbuf + 16384;           // 16,384
    float* fbuf = ctxbuf + 16384;           // 8,192
    float* inpbuf = fbuf + 8192;            // 16,384

    // --- weight transposes ---
    transpose_kernel<<<dim3(16, 16), 256, 0, stream>>>(Wq, WqT, 512, 512, 512);
    transpose_kernel<<<dim3(16, 16), 256, 0, stream>>>(Wk, WkT, 512, 512, 512);
    transpose_kernel<<<dim3(48, 16), 256, 0, stream>>>(Wi0, Wi0aT, 1536, 512, 1024);
    transpose_kernel<<<dim3(48, 16), 256, 0, stream>>>(Wi0 + 512, Wi0bT, 1536, 512, 1024);
    transpose_kernel<<<dim3(48, 16), 256, 0, stream>>>(Wh0, Wh0T, 1536, 512, 512);
    transpose_kernel<<<dim3(48, 16), 256, 0, stream>>>(Wi1, Wi1T, 1536, 512, 512);
    transpose_kernel<<<dim3(48, 16), 256, 0, stream>>>(Wh1, Wh1T, 1536, 512, 512);
    transpose_kernel<<<dim3(8, 16), 256, 0, stream>>>(last_W, lastWT, 256, 512, 512);
    transpose_kernel<<<dim3(16, 8), 256, 0, stream>>>(emb_W, embWT, 512, 256, 256);

    kproj_gemm_kernel<<<dim3(64, 8), 256, 0, stream>>>(enc, WkT, kpT);
    init_kernel<<<B, 512, 0, stream>>>(hidden, embWT, emb_b, h0buf, h1buf, inpbuf);

    int p0 = 0, p1 = 0;
    for (int i = 0; i < STEPS; ++i) {
        int im1 = (i > 0) ? i - 1 : 0;
        // qproj (+ lin of prev step when i>0)
        attn1_kernel<<<(i == 0) ? 128 : 160, 256, 0, stream>>>(
            128, h1buf + (size_t)p1 * BH, WqT, qbuf, lastWT, last_b,
            target + (size_t)im1 * B * ODIM, tmask + im1 * B, fbuf,
            out + (size_t)im1 * B * ODIM);
        // scores/softmax/ctx (+ emb of prev step when i>0)
        attn2_kernel<<<(i == 0) ? 32 : 64, 256, 0, stream>>>(
            32, qbuf, kpT, wv, enc, ctxbuf, out_attn + (size_t)i * B * T, fbuf, embWT, emb_b,
            inpbuf);
        // gi_ctx + gi_emb[i]
        gi_kernel<<<192, 256, 0, stream>>>(ctxbuf, Wi0aT, bi0, gi_ctx, inpbuf, Wi0bT,
                                           gi_emb + (size_t)i * B * G3);
        for (int t = 0; t <= i + 1; ++t) {
            int nb0 = (t <= i) ? 64 : 0;
            int nb1 = (t >= 1) ? 128 : 0;
            int tge = (t < 15) ? t : 15;
            cell_kernel<<<nb0 + nb1, 256, 0, stream>>>(
                nb0, h0buf + (size_t)p0 * BH, h0buf + (size_t)(p0 ^ 1) * BH,
                h1buf + (size_t)p1 * BH, h1buf + (size_t)(p1 ^ 1) * BH,
                gi_emb + (size_t)tge * B * G3, gi_ctx, Wh0T, bh0, Wi1T, bi1, Wh1T, bh1);
            if (nb0) p0 ^= 1;
            if (nb1) p1 ^= 1;
        }
    }
    // final lin (step 15)
    attn1_kernel<<<32, 256, 0, stream>>>(0, h1buf + (size_t)p1 * BH, WqT, qbuf, lastWT, last_b,
                                         target + (size_t)15 * B * ODIM, tmask + 15 * B, fbuf,
                                         out + (size_t)15 * B * ODIM);
    copy_hidden_kernel<<<64, 256, 0, stream>>>(h0buf + (size_t)p0 * BH, h1buf + (size_t)p1 * BH,
                                               out_hidden);
}